// Round 6
// baseline (132.877 us; speedup 1.0000x reference)
//
#include <hip/hip_runtime.h>
#include <hip/hip_bf16.h>
#include <hip/hip_fp8.h>

// ContrastiveLoss (SimCLR InfoNCE): N=8192, D=1024, T=0.1
// nll[i] = -logit[i, (i+N/2)%N] + logsumexp_j(logit[i,j]), diag masked out
// logit = cos_sim / T; out = mean(nll)
//
// Identities:
//  - zn_i = z_i * sqrt(10*log2e)/||z_i||  =>  dot d = logit*log2e and
//    exp(logit-10) = 2^(d - 10*log2e) -> raw v_exp_f32.
//  - logit in [-10,10] => FIXED-offset logsumexp; masked diagonal term is
//    exactly 0, handled only in the 64 diagonal supertiles.
//  - Gram symmetric: upper-tri 128x128 supertiles (2080 of 4096); off-diag
//    tile (I,J) adds exp row-sums to rows of I, col-sums to rows of J.
//  - positive-pair logits = tile diagonals of supertiles (I, I+32).
//  - MX-scaled fp8 K=128 MFMA with all scales = 1.0 (2x bf16 rate).
//
// R18: supercell L2 ordering (R17, confirmed: FETCH 66->23MB, gemm 65->56us)
// + R14's register ping-pong phase pipeline. Rationale: R13-R15's schedule
// nulls were measured UNDER the L2-miss-concurrency regime R17 removed
// (rule #23 - nulls in the wrong regime are uninterpretable). Post-fix,
// the serialized per-phase chain {16 ds_read_b128 (~192cy) -> lgkm(0) ->
// barrier -> 16 MFMA (~138cy)} is the candidate wall. R14's structure reads
// frags(p+1) from the other LDS buffer BEFORE the MFMA cluster of phase p:
// MFMAs consume registers with no lgkm wait, ds_reads hide under MFMA, one
// barrier per phase. B double-buffered (66KB LDS, 2 blocks/CU - occupancy
// proven irrelevant R11-R13). Predicted: gemm 56->45-48us, MfmaUtil ~30%;
// neutral => 2-barrier cadence itself is the wall -> 8-phase restructure.

#define N_ROWS 8192
#define DIM    1024
#define BM 128
#define BK 128                         // bytes (= elems) of K per phase
#define NPHASE (DIM / BK)              // 8
#define NT     (N_ROWS / BM)           // 64
#define NTILES (NT * (NT + 1) / 2)     // 2080
#define OFFS   14.4269504088896340f    // 10 * log2e
#define ROW_SCALE 3.7982825605f        // sqrt(10 * log2e)
#define LN2    0.6931471805599453f
#define LOGIT_MAX 10.0f
#define SCALE1 0x7F7F7F7F              // e8m0 1.0 in every byte

typedef float floatx4 __attribute__((ext_vector_type(4)));
typedef int   intx4   __attribute__((ext_vector_type(4)));
typedef int   intx8   __attribute__((ext_vector_type(8)));

__device__ __forceinline__ void async_copy16(const void* g, void* lds) {
  __builtin_amdgcn_global_load_lds(
      (const __attribute__((address_space(1))) void*)g,
      (__attribute__((address_space(3))) void*)lds, 16, 0, 0);
}

__device__ __forceinline__ unsigned pack4_e4m3(float a, float b, float c, float d) {
  __hip_fp8_e4m3 qa(a), qb(b), qc(c), qd(d);
  return (unsigned)qa.__x | ((unsigned)qb.__x << 8) |
         ((unsigned)qc.__x << 16) | ((unsigned)qd.__x << 24);
}

// ---------------- Kernel 1: row normalize -> fp8 (+ zero accumulators) ----
__global__ __launch_bounds__(256) void normalize_kernel(
    const float* __restrict__ z, unsigned char* __restrict__ zn,
    float* __restrict__ sumexp, float* __restrict__ out) {
  const int tid = threadIdx.x, wave = tid >> 6, lane = tid & 63;
  const int row = blockIdx.x * 4 + wave;

  if (blockIdx.x < 8) ((float4*)sumexp)[blockIdx.x * 256 + tid] = float4{0, 0, 0, 0};
  if (blockIdx.x == 8 && tid == 0) out[0] = 0.0f;

  const float4* zr = (const float4*)(z + (size_t)row * DIM);
  float4 v[4];
  #pragma unroll
  for (int j = 0; j < 4; j++) v[j] = zr[lane + 64 * j];
  float ss = 0.0f;
  #pragma unroll
  for (int j = 0; j < 4; j++)
    ss += v[j].x * v[j].x + v[j].y * v[j].y + v[j].z * v[j].z + v[j].w * v[j].w;
  #pragma unroll
  for (int off = 32; off > 0; off >>= 1) ss += __shfl_xor(ss, off);
  const float scale = rsqrtf(ss) * ROW_SCALE;  // norms ~32 >> eps

  unsigned* o = (unsigned*)(zn + (size_t)row * DIM);
  #pragma unroll
  for (int j = 0; j < 4; j++)
    o[lane + 64 * j] = pack4_e4m3(v[j].x * scale, v[j].y * scale,
                                  v[j].z * scale, v[j].w * scale);
}

// Supercell-major tile decode: 64x64 upper-tri grid partitioned into 8x8
// supercells (rows SI, cols SJ >= SI). Diag supercell = 36 tiles (upper-tri
// 8x8), off-diag = 64 (full 8x8). Cell-row SI holds 36 + (7-SI)*64 tiles;
// prefix P(SI) = 516*SI - 32*SI*SI (P(8)=2080). Within a cell-row: diag
// cell first, then off-diag cells with snake order (even SI: SJ ascending,
// odd SI: descending) so adjacent cells share B panels at row turns; all
// cells in a row share the same A panels. Within cell: row-major (i,j).
// Confirmed R17: FETCH 66->23MB, gemm 65.3->56.4us.
__device__ __forceinline__ void decode_tile(int g, int& I, int& J) {
  int SI = 0;
  #pragma unroll
  for (int s = 1; s < 8; ++s)
    if (516 * s - 32 * s * s <= g) SI = s;
  int rem = g - (516 * SI - 32 * SI * SI);
  int i, j, SJ;
  if (rem < 36) {                       // diagonal supercell, upper-tri 8x8
    SJ = SI;
    i = 0;
    while ((i + 1) * (17 - (i + 1)) / 2 <= rem) ++i;  // prefix(i)=i*(17-i)/2
    j = i + (rem - i * (17 - i) / 2);
  } else {                              // full off-diagonal supercell
    const int rem2 = rem - 36;
    const int cc = rem2 >> 6;           // 0 .. (6-SI)
    const int k  = rem2 & 63;
    SJ = (SI & 1) ? (7 - cc) : (SI + 1 + cc);
    i = k >> 3;
    j = k & 7;
  }
  I = SI * 8 + i;
  J = SJ * 8 + j;
}

// ---------------- Kernel 2: upper-tri MX-fp8 GEMM + partial sum-exp -------
__global__ __launch_bounds__(256, 2) void fused_gemm_lse(
    const unsigned char* __restrict__ zn, float* __restrict__ sumexp,
    float* __restrict__ pos) {
  __shared__ unsigned char sA[2][BM * BK];    // 2 x 16 KB (double buffer)
  __shared__ unsigned char sB[2][BM * BK];    // 2 x 16 KB (double buffer)
  __shared__ float rowRed[2][BM];             // 1 KB
  __shared__ float colRed[2][BM];             // 1 KB   (total 66 KB)

  const int tid  = threadIdx.x;
  const int lane = tid & 63;
  const int wave = tid >> 6;
  const int quad = lane >> 4;
  const int l15  = lane & 15;
  const int waveM = wave >> 1;  // 0..1
  const int waveN = wave & 1;   // 0..1

  // XCD-contiguous tile permutation (2080 = 8 * 260)
  const int t = (blockIdx.x & 7) * (NTILES / 8) + (blockIdx.x >> 3);
  int I, J;
  decode_tile(t, I, J);
  const int rowBase = I * BM, colBase = J * BM;

  // staging: 128x128B tile = 1024 16B-chunks, 4/thread/matrix.
  // chunk s: row r = s>>3, stored slot s&7 holds logical 16B k-chunk
  // q = (s&7) ^ (r&7)  (XOR swizzle, applied on the global-address side).
  const unsigned char* aP[4];
  const unsigned char* bP[4];
  int soff[4];
  #pragma unroll
  for (int i = 0; i < 4; i++) {
    const int s = i * 256 + tid;            // i*256 + wave*64 + lane
    const int r = s >> 3;                   // tile row 0..127
    const int q = (s & 7) ^ (r & 7);        // logical k-chunk 0..7
    aP[i] = zn + (size_t)(rowBase + r) * DIM + q * 16;
    bP[i] = zn + (size_t)(colBase + r) * DIM + q * 16;
    soff[i] = s * 16;                       // wave-uniform base + lane*16
  }
  auto stageA = [&](int buf) {
    #pragma unroll
    for (int i = 0; i < 4; i++) {
      async_copy16(aP[i], (char*)sA[buf] + soff[i]);
      aP[i] += BK;
    }
  };
  auto stageB = [&](int buf) {
    #pragma unroll
    for (int i = 0; i < 4; i++) {
      async_copy16(bP[i], (char*)sB[buf] + soff[i]);
      bP[i] += BK;
    }
  };

  floatx4 acc[4][4];
  #pragma unroll
  for (int mi = 0; mi < 4; mi++)
    #pragma unroll
    for (int ni = 0; ni < 4; ni++) acc[mi][ni] = {0.f, 0.f, 0.f, 0.f};

  // fragment readers: plain C++ LDS loads (compiler tracks reg deps)
  auto readFrags = [&](const unsigned char* bufA, const unsigned char* bufB,
                       intx8* aa, intx8* bb) {
    #pragma unroll
    for (int ni = 0; ni < 4; ni++) {
      const int r = waveN * 64 + ni * 16 + l15;
      const int c0 = (quad * 2) ^ (r & 7);
      const intx4 lo = *(const intx4*)(bufB + (r * 8 + c0) * 16);
      const intx4 hi = *(const intx4*)(bufB + (r * 8 + (c0 ^ 1)) * 16);
      bb[ni] = __builtin_shufflevector(lo, hi, 0, 1, 2, 3, 4, 5, 6, 7);
    }
    #pragma unroll
    for (int mi = 0; mi < 4; mi++) {
      const int r = waveM * 64 + mi * 16 + l15;
      const int c0 = (quad * 2) ^ (r & 7);
      const intx4 lo = *(const intx4*)(bufA + (r * 8 + c0) * 16);
      const intx4 hi = *(const intx4*)(bufA + (r * 8 + (c0 ^ 1)) * 16);
      aa[mi] = __builtin_shufflevector(lo, hi, 0, 1, 2, 3, 4, 5, 6, 7);
    }
  };
  auto mfmaC = [&](const intx8* aa, const intx8* bb) {
    __builtin_amdgcn_s_setprio(1);
    #pragma unroll
    for (int mi = 0; mi < 4; mi++)
      #pragma unroll
      for (int ni = 0; ni < 4; ni++)
        acc[mi][ni] = __builtin_amdgcn_mfma_scale_f32_16x16x128_f8f6f4(
            aa[mi], bb[ni], acc[mi][ni],
            0 /*cbsz: A=e4m3*/, 0 /*blgp: B=e4m3*/,
            0, SCALE1,   // opsel_a, scale_a = 1.0
            0, SCALE1);  // opsel_b, scale_b = 1.0
    __builtin_amdgcn_s_setprio(0);
  };

  // prologue: tiles 0 and 1 in flight; frags(0) hoisted to E registers
  stageA(0); stageB(0);
  stageA(1); stageB(1);
  asm volatile("s_waitcnt vmcnt(8)" ::: "memory");   // tile 0 LDS-resident
  __builtin_amdgcn_s_barrier();
  intx8 aaE[4], bbE[4], aaO[4], bbO[4];
  readFrags(&sA[0][0], &sB[0][0], aaE, bbE);
  asm volatile("s_waitcnt lgkmcnt(0)" ::: "memory"); // frags(0) in regs

  #pragma unroll
  for (int p = 0; p < NPHASE; p += 2) {
    // ---- even phase p: compute E, prefetch frags(p+1) into O ----
    asm volatile("s_waitcnt vmcnt(0)" ::: "memory"); // tile p+1 LDS-resident
    __builtin_amdgcn_s_barrier();                    // buf0 reads all done
    if (p + 2 < NPHASE) { stageA(0); stageB(0); }    // tile p+2 -> buf0
    readFrags(&sA[1][0], &sB[1][0], aaO, bbO);       // frags(p+1)
    mfmaC(aaE, bbE);                                 // overlaps ds_reads
    asm volatile("s_waitcnt lgkmcnt(0)" ::: "memory");
    // ---- odd phase p+1: compute O, prefetch frags(p+2) into E ----
    asm volatile("s_waitcnt vmcnt(0)" ::: "memory"); // tile p+2 LDS-resident
    __builtin_amdgcn_s_barrier();                    // buf1 reads all done
    if (p + 3 < NPHASE) { stageA(1); stageB(1); }    // tile p+3 -> buf1
    if (p + 2 < NPHASE) readFrags(&sA[0][0], &sB[0][0], aaE, bbE);
    mfmaC(aaO, bbO);
    asm volatile("s_waitcnt lgkmcnt(0)" ::: "memory");
  }

  // ---- epilogue ----
  // C/D layout (16x16 shape family): col = lane&15, row = quad*4 + reg
  const bool diagBlk = (I == J);

  if (J == I + 32 && waveM == waveN) {  // positive-pair supertile
    #pragma unroll
    for (int mi = 0; mi < 4; mi++)
      #pragma unroll
      for (int r = 0; r < 4; r++)
        if (l15 == quad * 4 + r)
          pos[rowBase + waveM * 64 + mi * 16 + l15] = acc[mi][mi][r];
  }

  float rsum[4][4], csum[4];
  #pragma unroll
  for (int mi = 0; mi < 4; mi++)
    #pragma unroll
    for (int r = 0; r < 4; r++) rsum[mi][r] = 0.0f;
  #pragma unroll
  for (int ni = 0; ni < 4; ni++) csum[ni] = 0.0f;

  if (diagBlk) {
    #pragma unroll
    for (int mi = 0; mi < 4; mi++)
      #pragma unroll
      for (int ni = 0; ni < 4; ni++) {
        const bool dtile = (waveM == waveN) && (mi == ni);
        #pragma unroll
        for (int r = 0; r < 4; r++) {
          float e = exp2f(acc[mi][ni][r] - OFFS);
          if (dtile && l15 == quad * 4 + r) e = 0.0f;  // masked diagonal
          rsum[mi][r] += e;
        }
      }
  } else {
    #pragma unroll
    for (int mi = 0; mi < 4; mi++)
      #pragma unroll
      for (int ni = 0; ni < 4; ni++)
        #pragma unroll
        for (int r = 0; r < 4; r++) {
          const float e = exp2f(acc[mi][ni][r] - OFFS);
          rsum[mi][r] += e;
          csum[ni]    += e;
        }
  }

  #pragma unroll
  for (int mi = 0; mi < 4; mi++)
    #pragma unroll
    for (int r = 0; r < 4; r++) {
      float v = rsum[mi][r];
      v += __shfl_xor(v, 1);
      v += __shfl_xor(v, 2);
      v += __shfl_xor(v, 4);
      v += __shfl_xor(v, 8);
      if (l15 == 0)
        rowRed[waveN][waveM * 64 + mi * 16 + quad * 4 + r] = v;
    }
  if (!diagBlk) {
    #pragma unroll
    for (int ni = 0; ni < 4; ni++) {
      float v = csum[ni];
      v += __shfl_xor(v, 16);
      v += __shfl_xor(v, 32);
      if (quad == 0)
        colRed[waveM][waveN * 64 + ni * 16 + l15] = v;
    }
  }
  __syncthreads();

  if (tid < BM) {
    atomicAdd(&sumexp[rowBase + tid], rowRed[0][tid] + rowRed[1][tid]);
  } else if (!diagBlk) {
    const int c = tid - BM;
    atomicAdd(&sumexp[colBase + c], colRed[0][c] + colRed[1][c]);
  }
}

// ---------------- Kernel 3: mean NLL --------------------------------------
__global__ __launch_bounds__(256) void finalize_kernel(
    const float* __restrict__ sumexp, const float* __restrict__ pos,
    float* __restrict__ out) {
  const int tid = threadIdx.x;
  const int row = blockIdx.x * 256 + tid;
  // pos holds d = logit*log2e for rows [0,4096); pos[i+4096] == pos[i]
  float local = -(pos[row & (N_ROWS / 2 - 1)] * LN2) + LOGIT_MAX + logf(sumexp[row]);
  #pragma unroll
  for (int off = 32; off > 0; off >>= 1) local += __shfl_xor(local, off);
  __shared__ float red[4];
  const int wave = tid >> 6, lane = tid & 63;
  if (lane == 0) red[wave] = local;
  __syncthreads();
  if (tid == 0)
    atomicAdd(out, (red[0] + red[1] + red[2] + red[3]) * (1.0f / N_ROWS));
}

extern "C" void kernel_launch(void* const* d_in, const int* in_sizes, int n_in,
                              void* d_out, int out_size, void* d_ws, size_t ws_size,
                              hipStream_t stream) {
  const float* z = (const float*)d_in[0];
  float* out = (float*)d_out;

  char* ws = (char*)d_ws;
  unsigned char* zn = (unsigned char*)ws;                    // 8 MB fp8
  float* sumexp = (float*)(ws + (size_t)N_ROWS * DIM);       // 32 KB
  float* pos    = sumexp + N_ROWS;                           // 16 KB

  normalize_kernel<<<N_ROWS / 4, 256, 0, stream>>>(z, zn, sumexp, out);
  fused_gemm_lse<<<NTILES, 256, 0, stream>>>(zn, sumexp, pos);
  finalize_kernel<<<N_ROWS / 256, 256, 0, stream>>>(sumexp, pos, out);
}

// Round 7
// 132.165 us; speedup vs baseline: 1.0054x; 1.0054x over previous
//
#include <hip/hip_runtime.h>
#include <hip/hip_bf16.h>
#include <hip/hip_fp8.h>

// ContrastiveLoss (SimCLR InfoNCE): N=8192, D=1024, T=0.1
// nll[i] = -logit[i, (i+N/2)%N] + logsumexp_j(logit[i,j]), diag masked out
// logit = cos_sim / T; out = mean(nll)
//
// Identities:
//  - zn_i = z_i * sqrt(10*log2e)/||z_i||  =>  dot d = logit*log2e and
//    exp(logit-10) = 2^(d - 10*log2e) -> raw v_exp_f32.
//  - logit in [-10,10] => FIXED-offset logsumexp; masked diagonal term is
//    exactly 0, handled only in the 64 diagonal supertiles.
//  - Gram symmetric: upper-tri 128x128 supertiles (2080 of 4096); off-diag
//    tile (I,J) adds exp row-sums to rows of I, col-sums to rows of J.
//  - positive-pair logits = tile diagonals of supertiles (I, I+32).
//  - MX-scaled fp8 K=128 MFMA with all scales = 1.0 (2x bf16 rate).
//
// R19: R17 skeleton + REG-STAGING (the only change vs R17; R18's ping-pong
// regressed 56->66us and is discarded). Evidence: R17's staging throughput
// is 15.4 B/cy/CU vs 13.2-13.5 in all miss-regime rounds -- the L2 fix
// bought +14% then re-pinned at ~16 B/cy => the global_load_lds DMA return
// path caps ~16 B/cy/CU. R15's reg-staging null was measured in the MISS
// regime (wall ~13.5 < DMA cap -- rule #23: uninterpretable here). No other
// resource is near saturation (MFMA 26%, LDS ~50% w/ conflicts, HBM 5%).
// Swap: global_load_dwordx4 -> X regs -> ds_write_b128. Same pre-swizzled
// global source, linear LDS slots, swizzled reads (rule #21). Bonus: global
// loads are thread-private => barriers are LGKM-ONLY, no vmcnt drain in the
// loop; X(p+1) loads get a full phase of latency slack. 50KB LDS, 3
// blocks/CU, supercell order kept. Predicted: staging >20 B/cy, gemm
// 56.4 -> 44-48us, MfmaUtil ~30%; neutral => DMA exonerated, wall = the
// 2-barrier lockstep cadence -> sub-phase interleave next.

#define N_ROWS 8192
#define DIM    1024
#define BM 128
#define BK 128                         // bytes (= elems) of K per phase
#define NPHASE (DIM / BK)              // 8
#define NT     (N_ROWS / BM)           // 64
#define NTILES (NT * (NT + 1) / 2)     // 2080
#define OFFS   14.4269504088896340f    // 10 * log2e
#define ROW_SCALE 3.7982825605f        // sqrt(10 * log2e)
#define LN2    0.6931471805599453f
#define LOGIT_MAX 10.0f
#define SCALE1 0x7F7F7F7F              // e8m0 1.0 in every byte

typedef float floatx4 __attribute__((ext_vector_type(4)));
typedef int   intx4   __attribute__((ext_vector_type(4)));
typedef int   intx8   __attribute__((ext_vector_type(8)));

__device__ __forceinline__ unsigned pack4_e4m3(float a, float b, float c, float d) {
  __hip_fp8_e4m3 qa(a), qb(b), qc(c), qd(d);
  return (unsigned)qa.__x | ((unsigned)qb.__x << 8) |
         ((unsigned)qc.__x << 16) | ((unsigned)qd.__x << 24);
}

// ---------------- Kernel 1: row normalize -> fp8 (+ zero accumulators) ----
__global__ __launch_bounds__(256) void normalize_kernel(
    const float* __restrict__ z, unsigned char* __restrict__ zn,
    float* __restrict__ sumexp, float* __restrict__ out) {
  const int tid = threadIdx.x, wave = tid >> 6, lane = tid & 63;
  const int row = blockIdx.x * 4 + wave;

  if (blockIdx.x < 8) ((float4*)sumexp)[blockIdx.x * 256 + tid] = float4{0, 0, 0, 0};
  if (blockIdx.x == 8 && tid == 0) out[0] = 0.0f;

  const float4* zr = (const float4*)(z + (size_t)row * DIM);
  float4 v[4];
  #pragma unroll
  for (int j = 0; j < 4; j++) v[j] = zr[lane + 64 * j];
  float ss = 0.0f;
  #pragma unroll
  for (int j = 0; j < 4; j++)
    ss += v[j].x * v[j].x + v[j].y * v[j].y + v[j].z * v[j].z + v[j].w * v[j].w;
  #pragma unroll
  for (int off = 32; off > 0; off >>= 1) ss += __shfl_xor(ss, off);
  const float scale = rsqrtf(ss) * ROW_SCALE;  // norms ~32 >> eps

  unsigned* o = (unsigned*)(zn + (size_t)row * DIM);
  #pragma unroll
  for (int j = 0; j < 4; j++)
    o[lane + 64 * j] = pack4_e4m3(v[j].x * scale, v[j].y * scale,
                                  v[j].z * scale, v[j].w * scale);
}

// Supercell-major tile decode: 64x64 upper-tri grid partitioned into 8x8
// supercells (rows SI, cols SJ >= SI). Diag supercell = 36 tiles (upper-tri
// 8x8), off-diag = 64 (full 8x8). Cell-row SI holds 36 + (7-SI)*64 tiles;
// prefix P(SI) = 516*SI - 32*SI*SI (P(8)=2080). Within a cell-row: diag
// cell first, then off-diag cells with snake order (even SI: SJ ascending,
// odd SI: descending) so adjacent cells share B panels at row turns; all
// cells in a row share the same A panels. Within cell: row-major (i,j).
// Confirmed R17: FETCH 66->23MB, gemm 65.3->56.4us.
__device__ __forceinline__ void decode_tile(int g, int& I, int& J) {
  int SI = 0;
  #pragma unroll
  for (int s = 1; s < 8; ++s)
    if (516 * s - 32 * s * s <= g) SI = s;
  int rem = g - (516 * SI - 32 * SI * SI);
  int i, j, SJ;
  if (rem < 36) {                       // diagonal supercell, upper-tri 8x8
    SJ = SI;
    i = 0;
    while ((i + 1) * (17 - (i + 1)) / 2 <= rem) ++i;  // prefix(i)=i*(17-i)/2
    j = i + (rem - i * (17 - i) / 2);
  } else {                              // full off-diagonal supercell
    const int rem2 = rem - 36;
    const int cc = rem2 >> 6;           // 0 .. (6-SI)
    const int k  = rem2 & 63;
    SJ = (SI & 1) ? (7 - cc) : (SI + 1 + cc);
    i = k >> 3;
    j = k & 7;
  }
  I = SI * 8 + i;
  J = SJ * 8 + j;
}

// ---------------- Kernel 2: upper-tri MX-fp8 GEMM + partial sum-exp -------
__global__ __launch_bounds__(256, 3) void fused_gemm_lse(
    const unsigned char* __restrict__ zn, float* __restrict__ sumexp,
    float* __restrict__ pos) {
  __shared__ unsigned char sA[2][BM * BK];    // 2 x 16 KB (double buffer)
  __shared__ unsigned char sB[BM * BK];       // 16 KB (single buffer)
  __shared__ float rowRed[2][BM];             // 1 KB
  __shared__ float colRed[2][BM];             // 1 KB   (total 50 KB)

  const int tid  = threadIdx.x;
  const int lane = tid & 63;
  const int wave = tid >> 6;
  const int quad = lane >> 4;
  const int l15  = lane & 15;
  const int waveM = wave >> 1;  // 0..1
  const int waveN = wave & 1;   // 0..1

  // XCD-contiguous tile permutation (2080 = 8 * 260)
  const int t = (blockIdx.x & 7) * (NTILES / 8) + (blockIdx.x >> 3);
  int I, J;
  decode_tile(t, I, J);
  const int rowBase = I * BM, colBase = J * BM;

  // staging: 128x128B tile = 1024 16B-chunks, 4/thread/matrix.
  // chunk s: row r = s>>3, stored slot s&7 holds logical 16B k-chunk
  // q = (s&7) ^ (r&7)  (XOR swizzle, applied on the global-address side).
  const unsigned char* aP[4];
  const unsigned char* bP[4];
  int soff[4];
  #pragma unroll
  for (int i = 0; i < 4; i++) {
    const int s = i * 256 + tid;            // i*256 + wave*64 + lane
    const int r = s >> 3;                   // tile row 0..127
    const int q = (s & 7) ^ (r & 7);        // logical k-chunk 0..7
    aP[i] = zn + (size_t)(rowBase + r) * DIM + q * 16;
    bP[i] = zn + (size_t)(colBase + r) * DIM + q * 16;
    soff[i] = s * 16;                       // wave-uniform base + lane*16
  }

  // reg-staging: global -> X (thread-private, no barrier semantics) ->
  // ds_write_b128 at the staging point. A-half in X[0..3], B in X[4..7].
  intx4 X[8];
  auto loadX = [&]() {                      // loads next phase, ptrs advance
    #pragma unroll
    for (int i = 0; i < 4; i++) { X[i]     = *(const intx4*)aP[i]; aP[i] += BK; }
    #pragma unroll
    for (int i = 0; i < 4; i++) { X[4 + i] = *(const intx4*)bP[i]; bP[i] += BK; }
  };
  auto writeStage = [&](int buf) {          // X -> LDS (linear slots)
    #pragma unroll
    for (int i = 0; i < 4; i++) *(intx4*)(&sA[buf][soff[i]]) = X[i];
    #pragma unroll
    for (int i = 0; i < 4; i++) *(intx4*)(&sB[soff[i]])      = X[4 + i];
  };

  floatx4 acc[4][4];
  #pragma unroll
  for (int mi = 0; mi < 4; mi++)
    #pragma unroll
    for (int ni = 0; ni < 4; ni++) acc[mi][ni] = {0.f, 0.f, 0.f, 0.f};

  // prologue: phase 0 -> LDS; phase 1 loads left in flight in X
  loadX();                               // phase 0
  writeStage(0);                         // compiler waits vmcnt for X
  loadX();                               // phase 1 (in flight across loop)
  asm volatile("s_waitcnt lgkmcnt(0)\ns_barrier" ::: "memory");  // ph0 ready

  for (int p = 0; p < NPHASE; ++p) {
    const int b = p & 1;

    // hoist B[p] fragments to registers (sB re-staged after the barrier)
    intx8 bb[4];
    #pragma unroll
    for (int ni = 0; ni < 4; ni++) {
      const int r = waveN * 64 + ni * 16 + l15;
      const int c0 = (quad * 2) ^ (r & 7);
      const intx4 lo = *(const intx4*)(&sB[0] + (r * 8 + c0) * 16);
      const intx4 hi = *(const intx4*)(&sB[0] + (r * 8 + (c0 ^ 1)) * 16);
      bb[ni] = __builtin_shufflevector(lo, hi, 0, 1, 2, 3, 4, 5, 6, 7);
    }
    // all waves done with sB and sA[b^1]; lgkm-only drain (no vmcnt!)
    asm volatile("s_waitcnt lgkmcnt(0)\ns_barrier" ::: "memory");

    if (p + 1 < NPHASE) writeStage(b ^ 1);  // phase p+1 -> LDS (waits X vmcnt)
    if (p + 2 < NPHASE) loadX();            // phase p+2 -> X (stays in flight)

    #pragma unroll
    for (int mi = 0; mi < 4; mi++) {
      const int r = waveM * 64 + mi * 16 + l15;
      const int c0 = (quad * 2) ^ (r & 7);
      const intx4 lo = *(const intx4*)(&sA[b][0] + (r * 8 + c0) * 16);
      const intx4 hi = *(const intx4*)(&sA[b][0] + (r * 8 + (c0 ^ 1)) * 16);
      const intx8 a = __builtin_shufflevector(lo, hi, 0, 1, 2, 3, 4, 5, 6, 7);
      #pragma unroll
      for (int ni = 0; ni < 4; ni++)
        acc[mi][ni] = __builtin_amdgcn_mfma_scale_f32_16x16x128_f8f6f4(
            a, bb[ni], acc[mi][ni],
            0 /*cbsz: A=e4m3*/, 0 /*blgp: B=e4m3*/,
            0, SCALE1,   // opsel_a, scale_a = 1.0
            0, SCALE1);  // opsel_b, scale_b = 1.0
    }
    // my ds_writes (phase p+1) + my LDS reads drained -> next phase ready
    asm volatile("s_waitcnt lgkmcnt(0)\ns_barrier" ::: "memory");
  }

  // ---- epilogue ----
  // C/D layout (16x16 shape family): col = lane&15, row = quad*4 + reg
  const bool diagBlk = (I == J);

  if (J == I + 32 && waveM == waveN) {  // positive-pair supertile
    #pragma unroll
    for (int mi = 0; mi < 4; mi++)
      #pragma unroll
      for (int r = 0; r < 4; r++)
        if (l15 == quad * 4 + r)
          pos[rowBase + waveM * 64 + mi * 16 + l15] = acc[mi][mi][r];
  }

  float rsum[4][4], csum[4];
  #pragma unroll
  for (int mi = 0; mi < 4; mi++)
    #pragma unroll
    for (int r = 0; r < 4; r++) rsum[mi][r] = 0.0f;
  #pragma unroll
  for (int ni = 0; ni < 4; ni++) csum[ni] = 0.0f;

  if (diagBlk) {
    #pragma unroll
    for (int mi = 0; mi < 4; mi++)
      #pragma unroll
      for (int ni = 0; ni < 4; ni++) {
        const bool dtile = (waveM == waveN) && (mi == ni);
        #pragma unroll
        for (int r = 0; r < 4; r++) {
          float e = exp2f(acc[mi][ni][r] - OFFS);
          if (dtile && l15 == quad * 4 + r) e = 0.0f;  // masked diagonal
          rsum[mi][r] += e;
        }
      }
  } else {
    #pragma unroll
    for (int mi = 0; mi < 4; mi++)
      #pragma unroll
      for (int ni = 0; ni < 4; ni++)
        #pragma unroll
        for (int r = 0; r < 4; r++) {
          const float e = exp2f(acc[mi][ni][r] - OFFS);
          rsum[mi][r] += e;
          csum[ni]    += e;
        }
  }

  #pragma unroll
  for (int mi = 0; mi < 4; mi++)
    #pragma unroll
    for (int r = 0; r < 4; r++) {
      float v = rsum[mi][r];
      v += __shfl_xor(v, 1);
      v += __shfl_xor(v, 2);
      v += __shfl_xor(v, 4);
      v += __shfl_xor(v, 8);
      if (l15 == 0)
        rowRed[waveN][waveM * 64 + mi * 16 + quad * 4 + r] = v;
    }
  if (!diagBlk) {
    #pragma unroll
    for (int ni = 0; ni < 4; ni++) {
      float v = csum[ni];
      v += __shfl_xor(v, 16);
      v += __shfl_xor(v, 32);
      if (quad == 0)
        colRed[waveM][waveN * 64 + ni * 16 + l15] = v;
    }
  }
  __syncthreads();

  if (tid < BM) {
    atomicAdd(&sumexp[rowBase + tid], rowRed[0][tid] + rowRed[1][tid]);
  } else if (!diagBlk) {
    const int c = tid - BM;
    atomicAdd(&sumexp[colBase + c], colRed[0][c] + colRed[1][c]);
  }
}

// ---------------- Kernel 3: mean NLL --------------------------------------
__global__ __launch_bounds__(256) void finalize_kernel(
    const float* __restrict__ sumexp, const float* __restrict__ pos,
    float* __restrict__ out) {
  const int tid = threadIdx.x;
  const int row = blockIdx.x * 256 + tid;
  // pos holds d = logit*log2e for rows [0,4096); pos[i+4096] == pos[i]
  float local = -(pos[row & (N_ROWS / 2 - 1)] * LN2) + LOGIT_MAX + logf(sumexp[row]);
  #pragma unroll
  for (int off = 32; off > 0; off >>= 1) local += __shfl_xor(local, off);
  __shared__ float red[4];
  const int wave = tid >> 6, lane = tid & 63;
  if (lane == 0) red[wave] = local;
  __syncthreads();
  if (tid == 0)
    atomicAdd(out, (red[0] + red[1] + red[2] + red[3]) * (1.0f / N_ROWS));
}

extern "C" void kernel_launch(void* const* d_in, const int* in_sizes, int n_in,
                              void* d_out, int out_size, void* d_ws, size_t ws_size,
                              hipStream_t stream) {
  const float* z = (const float*)d_in[0];
  float* out = (float*)d_out;

  char* ws = (char*)d_ws;
  unsigned char* zn = (unsigned char*)ws;                    // 8 MB fp8
  float* sumexp = (float*)(ws + (size_t)N_ROWS * DIM);       // 32 KB
  float* pos    = sumexp + N_ROWS;                           // 16 KB

  normalize_kernel<<<N_ROWS / 4, 256, 0, stream>>>(z, zn, sumexp, out);
  fused_gemm_lse<<<NTILES, 256, 0, stream>>>(zn, sumexp, pos);
  finalize_kernel<<<N_ROWS / 256, 256, 0, stream>>>(sumexp, pos, out);
}